// Round 10
// baseline (22425.446 us; speedup 1.0000x reference)
//
#include <hip/hip_runtime.h>
#include <stdint.h>

// GRU acoustic model, fp32 I/O. R10: 64 CUs x 1 batch row each.
// R9 post-mortem: redistribution worked (absmax bit-identical) but two
// serial per-step costs remained: (a) x staging's global load issued and
// consumed in the SAME step -> ~700cyc HBM latency on every barrier chain;
// (b) epilogue scaled with 4 rows/CU (3 elem/lane, 4-row byte-interleaved
// ds_write_b8 conflicts). Both scale with rows; MFMA doesn't. R10: 64 WGs
// x 1 row (4x CUs), register-pipelined x prefetch (load x[t+1] at step t,
// write the long-arrived x[t] to LDS), <=1 epilogue element/lane, 8th
// gate-block in registers on wave 0 (no LDS weight path). Zero cross-CU
// traffic; 2 barriers/step. fc fused; decoder kernel unchanged (proven).
#define FEAT 13
#define EMB 300
#define BATCH 64
#define TSTEPS 2048
#define NCOL 304            // 19 slices x 16 gate cols (300 + 4 pad)
#define KI8 320             // i8 K per hbuf row (300 + pad)
#define QW  2199.7045f      // 127*sqrt(300)
#define SWH 3.5795795e-6f   // 1/(127*127*sqrt(300))

typedef float  floatx4 __attribute__((ext_vector_type(4)));
typedef short  shortx8 __attribute__((ext_vector_type(8)));
typedef int    intx4   __attribute__((ext_vector_type(4)));

__device__ __forceinline__ uint16_t f2b(float f) {
  union { float f; uint32_t i; } c; c.f = f;
  uint32_t r = c.i + 0x7fffu + ((c.i >> 16) & 1u);
  return (uint16_t)(r >> 16);
}
__device__ __forceinline__ float sigf(float x) {
  return __builtin_amdgcn_rcpf(1.f + __expf(-x));
}
__device__ __forceinline__ float tanhf_(float x) {
  return 1.f - 2.f * __builtin_amdgcn_rcpf(1.f + __expf(2.f * x));
}
__device__ __forceinline__ int q8w(float v) {
  return __float2int_rn(fminf(fmaxf(v * QW, -127.f), 127.f));
}

#define MFI8(A, B, C) __builtin_amdgcn_mfma_i32_16x16x64_i8(A, B, C, 0, 0, 0)
#define MFBF(A, B, C) __builtin_amdgcn_mfma_f32_16x16x32_bf16(A, B, C, 0, 0, 0)

__launch_bounds__(512, 2)
__global__ void gru_enc(const float* __restrict__ x,     // [64][2048][13]
                        const float* __restrict__ eWih,  // [900][13]
                        const float* __restrict__ eWhh,  // [900][300]
                        const float* __restrict__ ebih,  // [900]
                        const float* __restrict__ ebhh,  // [900]
                        const float* __restrict__ fcW,   // [300][300]
                        const float* __restrict__ fcb,   // [300]
                        float* __restrict__ out) {
  __shared__ __align__(16) signed char hbuf[2][16][KI8];   // 10240 B
  __shared__ __align__(16) uint16_t    xt[2][16][32];      // 2048 B
  __shared__ __align__(16) float       scr[4][NCOL];       // 4864 B

  const int tid = threadIdx.x, lane = tid & 63, w = tid >> 6;
  const int nl = lane & 15, q = lane >> 4;
  const int g = blockIdx.x;          // batch row

  // ---- one-time: register gate-blocks (7/wave; wave 0 gets 8th = block 56)
  const int NB = (w == 0) ? 8 : 7;
  intx4   Bh[8][5];
  shortx8 Bx[8];
  float   bA[8], bB[8];
#pragma unroll
  for (int k = 0; k < 8; ++k) {
    if (k >= NB) break;                 // wave-uniform
    int b = (k < 7) ? (7 * w + k) : 56;
    int s = b / 3, gt = b - 3 * s;
    int jj = 16 * s + nl;
    bool jvv = (jj < EMB);
    int R = gt * EMB + (jvv ? jj : 0);
    for (int kt = 0; kt < 5; ++kt) {
      int bb[4] = {0, 0, 0, 0};
      for (int e = 0; e < 16; ++e) {
        int kk = kt * 64 + q * 16 + e;
        float v = (jvv && kk < EMB) ? eWhh[(size_t)R * EMB + kk] : 0.f;
        bb[e >> 2] |= (q8w(v) & 255) << ((e & 3) * 8);
      }
      intx4 t4; t4[0] = bb[0]; t4[1] = bb[1]; t4[2] = bb[2]; t4[3] = bb[3];
      Bh[k][kt] = t4;
    }
    union { uint16_t u[8]; shortx8 v; } c;
    for (int e = 0; e < 8; ++e) {
      int kk = q * 8 + e;
      c.u[e] = (jvv && kk < FEAT) ? f2b(eWih[R * FEAT + kk]) : (uint16_t)0;
    }
    Bx[k] = c.v;
    if (gt == 2) {
      bA[k] = jvv ? ebhh[2 * EMB + jj] : 0.f;   // hn bias
      bB[k] = jvv ? ebih[2 * EMB + jj] : 0.f;   // in bias
    } else {
      bA[k] = jvv ? (ebih[gt * EMB + jj] + ebhh[gt * EMB + jj]) : 0.f;
      bB[k] = 0.f;
    }
  }

  // ---- init LDS: zero h/x buffers, stage x_0, preload x_1 into regs ----
  for (int i = tid; i < 2 * 16 * KI8; i += 512) ((signed char*)hbuf)[i] = 0;
  for (int i = tid; i < 2 * 16 * 32; i += 512) ((uint16_t*)xt)[i] = 0;
  __syncthreads();
  if (tid < FEAT)
    xt[0][0][tid] = f2b(x[((size_t)g * TSTEPS) * FEAT + tid]);
  float xreg = 0.f;   // wave 7 lanes<13: holds x[t] during step t (pipelined)
  if (w == 7 && lane < FEAT)
    xreg = x[((size_t)g * TSTEPS + 1) * FEAT + lane];
  __syncthreads();

  float hprev = 0.f;   // lane tid<NCOL owns h[tid] (fp32 carry)

  // ================= recurrence: 2 barriers/step, all on-CU =================
  for (int t = 1; t <= TSTEPS; ++t) {
    const int p = (t - 1) & 1, pn = t & 1;

    // A fragments (h_{t-1} i8, x_{t-1} bf16)
    intx4 Ah[5];
#pragma unroll
    for (int kt = 0; kt < 5; ++kt)
      Ah[kt] = *(const intx4*)&hbuf[p][nl][kt * 64 + q * 16];
    shortx8 Ax = *(const shortx8*)&xt[p][nl][q * 8];

    // wave 7: write the register-pipelined x[t] (loaded a full step ago;
    // no latency exposure), then issue the load of x[t+1]
    if (w == 7 && lane < FEAT) {
      if (t < TSTEPS) xt[pn][0][lane] = f2b(xreg);
      if (t + 1 < TSTEPS)
        xreg = x[((size_t)g * TSTEPS + (t + 1)) * FEAT + lane];
    }

    // MFMA per gate-block -> pre-activations (+bias) into scr (row 0 only)
#pragma unroll
    for (int k = 0; k < 8; ++k) {
      if (k >= NB) break;               // wave-uniform
      int b = (k < 7) ? (7 * w + k) : 56;
      int s = b / 3, gt = b - 3 * s;
      intx4 ai = {0, 0, 0, 0};
#pragma unroll
      for (int kt = 0; kt < 5; ++kt) ai = MFI8(Ah[kt], Bh[k][kt], ai);
      floatx4 ax = {0.f, 0.f, 0.f, 0.f};
      ax = MFBF(Ax, Bx[k], ax);
      if (q == 0) {                     // D row 0 lives in q==0, i==0
        int jj = 16 * s + nl;
        if (gt == 2) {
          scr[2][jj] = (float)ai[0] * SWH + bA[k];
          scr[3][jj] = ax[0] + bB[k];
        } else {
          scr[gt][jj] = (float)ai[0] * SWH + ax[0] + bA[k];
        }
      }
    }
    __syncthreads();   // B1: scr complete

    // epilogue: lane tid<NCOL owns one hidden column
    if (tid < NCOL) {
      float pr  = scr[0][tid];
      float pz  = scr[1][tid];
      float hn  = scr[2][tid];
      float in_ = scr[3][tid];
      float r = sigf(pr), z = sigf(pz);
      float n = tanhf_(in_ + r * hn);
      float h = z * (hprev - n) + n;
      hprev = h;
      float hq = fminf(fmaxf(h * 127.f, -127.f), 127.f);
      hbuf[pn][0][tid] = (signed char)__float2int_rn(hq);
    }
    __syncthreads();   // B2: h_t complete
  }

  // ================= fc: emb = relu(h_T @ fcW^T + fcb) =================
  {
    float* oemb = out + (size_t)BATCH * TSTEPS * FEAT;
    intx4 AhT[5];
#pragma unroll
    for (int kt = 0; kt < 5; ++kt)
      AhT[kt] = *(const intx4*)&hbuf[0][nl][kt * 64 + q * 16];  // T even
    for (int u = 0; u < 3; ++u) {
      int s = w + u * 8;
      if (s >= 19) break;     // wave-uniform
      int jj = 16 * s + nl;
      bool jvv = (jj < EMB);
      intx4 acc = {0, 0, 0, 0};
      for (int kt = 0; kt < 5; ++kt) {
        int bb[4] = {0, 0, 0, 0};
        for (int e = 0; e < 16; ++e) {
          int kk = kt * 64 + q * 16 + e;
          float v = (jvv && kk < EMB) ? fcW[(size_t)jj * EMB + kk] : 0.f;
          bb[e >> 2] |= (q8w(v) & 255) << ((e & 3) * 8);
        }
        intx4 b4; b4[0] = bb[0]; b4[1] = bb[1]; b4[2] = bb[2]; b4[3] = bb[3];
        acc = MFI8(AhT[kt], b4, acc);
      }
      if (q == 0 && jvv) {
        float e2 = (float)acc[0] * SWH + fcb[jj];
        oemb[(size_t)g * EMB + jj] = e2 > 0.f ? e2 : 0.f;
      }
    }
  }
}

// ---------------- decoder: 1 wave per batch, all fp32 (proven) --------------
__launch_bounds__(64, 1)
__global__ void gru_dec(const float* __restrict__ dWih,  // [39][300]
                        const float* __restrict__ dWhh,  // [39][13]
                        const float* __restrict__ dbih,  // [39]
                        const float* __restrict__ dbhh,  // [39]
                        float* __restrict__ out) {
  const int b  = blockIdx.x;
  const int lj = threadIdx.x;            // [0,13)=r [13,26)=z [26,39)=n
  const float* emb = out + (size_t)BATCH * TSTEPS * FEAT + (size_t)b * EMB;

  float Wd[FEAT];
#pragma unroll
  for (int k = 0; k < FEAT; ++k) Wd[k] = 0.f;
  float bhhv = 0.f, dgi = 0.f;
  if (lj < 3 * FEAT) {
#pragma unroll
    for (int k = 0; k < FEAT; ++k) Wd[k] = dWhh[lj * FEAT + k];
    bhhv = dbhh[lj];
    dgi  = dbih[lj];
#pragma unroll 4
    for (int k = 0; k < EMB; ++k)
      dgi = fmaf(emb[k], dWih[lj * EMB + k], dgi);
  }

  float hrep[FEAT];
#pragma unroll
  for (int k = 0; k < FEAT; ++k) hrep[k] = 0.f;
  float hown = 0.f;
  const bool nlane = (lj >= 2 * FEAT && lj < 3 * FEAT);
  float* orow = out + (size_t)b * TSTEPS * FEAT;

  for (int t = 0; t < TSTEPS; ++t) {
    float gh = bhhv;
#pragma unroll
    for (int k = 0; k < FEAT; ++k) gh = fmaf(Wd[k], hrep[k], gh);
    float sg = sigf(dgi + gh);
    float rr = __shfl(sg, (lj - 2 * FEAT) & 63);
    float zz = __shfl(sg, (lj - FEAT) & 63);
    float nn = tanhf_(dgi + rr * gh);
    float hn = zz * (hown - nn) + nn;
    bool same = (!nlane) || (hn == hown);
    if (nlane) {
      orow[t * FEAT + (lj - 2 * FEAT)] = hn;
      hown = hn;
    }
#pragma unroll
    for (int k = 0; k < FEAT; ++k) hrep[k] = __shfl(hown, 2 * FEAT + k);
    if (__all(same)) {  // exact fp32 fixed point -> rest constant
      if (nlane) {
        for (int t2 = t + 1; t2 < TSTEPS; ++t2)
          orow[t2 * FEAT + (lj - 2 * FEAT)] = hn;
      }
      break;
    }
  }
}

extern "C" void kernel_launch(void* const* d_in, const int* in_sizes, int n_in,
                              void* d_out, int out_size, void* d_ws, size_t ws_size,
                              hipStream_t stream) {
  (void)in_sizes; (void)n_in; (void)out_size; (void)d_ws; (void)ws_size;
  const float* x    = (const float*)d_in[0];
  const float* eWih = (const float*)d_in[1];
  const float* eWhh = (const float*)d_in[2];
  const float* ebih = (const float*)d_in[3];
  const float* ebhh = (const float*)d_in[4];
  const float* fcW  = (const float*)d_in[5];
  const float* fcb  = (const float*)d_in[6];
  const float* dWih = (const float*)d_in[7];
  const float* dWhh = (const float*)d_in[8];
  const float* dbih = (const float*)d_in[9];
  const float* dbhh = (const float*)d_in[10];

  hipLaunchKernelGGL(gru_enc, dim3(BATCH), dim3(512), 0, stream,
                     x, eWih, eWhh, ebih, ebhh, fcW, fcb, (float*)d_out);
  hipLaunchKernelGGL(gru_dec, dim3(BATCH), dim3(64), 0, stream,
                     dWih, dWhh, dbih, dbhh, (float*)d_out);
}